// Round 1
// baseline (535.083 us; speedup 1.0000x reference)
//
#include <hip/hip_runtime.h>
#include <hip/hip_bf16.h>

typedef unsigned short u16;
typedef __bf16  bf16x8 __attribute__((ext_vector_type(8)));
typedef float   f32x4  __attribute__((ext_vector_type(4)));

#define T_TOK 4096   // B*S tokens
#define DIN   4096
#define DOUT  4096
#define NEXP  8
#define ER    128    // E*R
#define SPLIT 8
#define KCH   (DIN / SPLIT)   // 512

// ws layout (bytes)
#define OFF_XB    0u           // bf16 x            33,554,432
#define OFF_WB    33554432u    // bf16 base_w       33,554,432
#define OFF_AB    67108864u    // bf16 lora_A flat   1,048,576
#define OFF_BS2   68157440u    // bf16 2*lora_B^T    1,048,576
#define OFF_U     69206016u    // bf16 U             1,048,576
#define OFF_BBF   70254592u    // fp32 bias             16,384
#define OFF_LG    70270976u    // fp32 logits          131,072
#define OFF_GPART 70402048u    // fp32 partials     16,777,216  -> end 87,179,264

__device__ __forceinline__ void async16(void* lds, const void* g) {
    __builtin_amdgcn_global_load_lds(
        (const __attribute__((address_space(1))) void*)g,
        (__attribute__((address_space(3))) void*)lds,
        16, 0, 0);
}

static __device__ __forceinline__ u16 f2b(float f) {
    __hip_bfloat16 h = __float2bfloat16(f);
    return *(u16*)&h;
}

// XOR-swizzled LDS read (128B rows, used by gemm1): slot (row, g') holds global
// column-group g'^ (row&7).
__device__ __forceinline__ bf16x8 lds8(const u16* base, int row, int grp) {
    return *(const bf16x8*)((const char*)base + row * 128 + (((grp ^ row) & 7) * 16));
}

// scheduling / sync primitives for the counted-vmcnt pipeline
#define FENCE() asm volatile("" ::: "memory")
#define RAW_BAR() do { FENCE(); __builtin_amdgcn_s_barrier(); FENCE(); } while (0)
#define LGKM0() do { asm volatile("s_waitcnt lgkmcnt(0)" ::: "memory"); \
                     __builtin_amdgcn_sched_barrier(0); } while (0)
#define WAITV(N) do { asm volatile("s_waitcnt vmcnt(" #N ")" ::: "memory"); \
                      __builtin_amdgcn_sched_barrier(0); } while (0)

// ---------------- convert fp32 -> bf16: x and base_w (8 elems/thread)
__global__ __launch_bounds__(256) void convert_big(const float* __restrict__ x,
                                                   const float* __restrict__ w,
                                                   uint4* __restrict__ xb,
                                                   uint4* __restrict__ wb) {
    int gid = blockIdx.x * 256 + threadIdx.x;          // 2 * 2,097,152 threads
    const float4* s = (const float4*)((gid < 2097152) ? x : w);
    uint4* dst      = (gid < 2097152) ? xb : wb;
    int li = gid & 2097151;
    float4 a = s[2 * li], b = s[2 * li + 1];
    uint4 o;
    o.x = (unsigned)f2b(a.x) | ((unsigned)f2b(a.y) << 16);
    o.y = (unsigned)f2b(a.z) | ((unsigned)f2b(a.w) << 16);
    o.z = (unsigned)f2b(b.x) | ((unsigned)f2b(b.y) << 16);
    o.w = (unsigned)f2b(b.z) | ((unsigned)f2b(b.w) << 16);
    dst[li] = o;
}

// ---------------- small packs: lora_A (bf16), 2*lora_B^T (bf16), bias (fp32)
__global__ __launch_bounds__(256) void pack_small(const float* __restrict__ lora_A,
                                                  const float* __restrict__ lora_B,
                                                  const float* __restrict__ base_b,
                                                  u16* __restrict__ ab,
                                                  u16* __restrict__ bs2,
                                                  float* __restrict__ bbf) {
    int idx = blockIdx.x * 256 + threadIdx.x;   // total 1,052,672
    if (idx < 524288) {                          // lora_A flat copy [e*16+r][d]
        ab[idx] = f2b(lora_A[idx]);
    } else if (idx < 1048576) {                  // bs2[o, e*16+r] = 2*lora_B[e,o,r]
        int j = idx - 524288;
        int o = j >> 7, c = j & 127, e = c >> 4, r = c & 15;
        bs2[j] = f2b(lora_B[(e * DOUT + o) * 16 + r] * 2.0f);
    } else if (idx < 1052672) {
        int j = idx - 1048576;
        bbf[j] = base_b[j];
    }
}

// ---------------- fp32 gate logits: 4 tokens per wave (gate_w load reuse) ----------------
__global__ __launch_bounds__(256) void gate_logits(const float* __restrict__ x,
                                                   const float* __restrict__ gw,
                                                   float* __restrict__ Lg) {
    const int w = threadIdx.x >> 6, lid = threadIdx.x & 63;
    const int t0 = (blockIdx.x * 4 + w) * 4;
    float acc[4][8];
#pragma unroll
    for (int j = 0; j < 4; ++j)
#pragma unroll
        for (int e = 0; e < 8; ++e) acc[j][e] = 0.f;
    for (int i = lid; i < DIN / 4; i += 64) {
        float4 gv[8];
#pragma unroll
        for (int e = 0; e < 8; ++e)
            gv[e] = ((const float4*)(gw + (size_t)e * DIN))[i];
#pragma unroll
        for (int j = 0; j < 4; ++j) {
            float4 xv = ((const float4*)(x + (size_t)(t0 + j) * DIN))[i];
#pragma unroll
            for (int e = 0; e < 8; ++e)
                acc[j][e] += xv.x * gv[e].x + xv.y * gv[e].y + xv.z * gv[e].z + xv.w * gv[e].w;
        }
    }
#pragma unroll
    for (int j = 0; j < 4; ++j)
#pragma unroll
        for (int e = 0; e < 8; ++e) {
            float v = acc[j][e];
            for (int off = 32; off; off >>= 1) v += __shfl_down(v, off, 64);
            if (lid == 0) Lg[(t0 + j) * 8 + e] = v;
        }
}

// ---------------- GEMM1: Gpart[s] = X @ lora_A^T, split-K fp32 partials
// grid (32 mb, 8 split), block 256. Tile 128(M) x 128(N) x 64(K).
__global__ __launch_bounds__(256) void gemm1(const u16* __restrict__ X,
                                             const u16* __restrict__ ab,
                                             float* __restrict__ Gpart) {
    __shared__ __align__(16) u16 As[128 * 64];
    __shared__ __align__(16) u16 Bs[128 * 64];
    const int mb = blockIdx.x, s = blockIdx.y;
    const int w = threadIdx.x >> 6, lid = threadIdx.x & 63;
    const int lrow = lid >> 3;                    // row within 8-row chunk
    const int lcolb = ((lid & 7) ^ lrow) * 16;    // swizzled source column group

    f32x4 acc[2][8];
#pragma unroll
    for (int i = 0; i < 2; ++i)
#pragma unroll
        for (int j = 0; j < 8; ++j) acc[i][j] = (f32x4){0.f, 0.f, 0.f, 0.f};

    int k0 = s * KCH;
    for (int kt = 0; kt < KCH / 64; ++kt, k0 += 64) {
#pragma unroll
        for (int q = 0; q < 4; ++q) {
            int c = w * 4 + q;
            int arow = mb * 128 + c * 8 + lrow;
            async16((char*)As + c * 1024,
                    (const char*)X + ((size_t)arow * DIN + k0) * 2 + lcolb);
            async16((char*)Bs + c * 1024,
                    (const char*)ab + ((size_t)(c * 8 + lrow) * DIN + k0) * 2 + lcolb);
        }
        __syncthreads();
        const int quad = lid >> 4, half = lid & 15;
#pragma unroll
        for (int ks8 = 0; ks8 < 8; ks8 += 4) {
            bf16x8 a[2], b[8];
#pragma unroll
            for (int i = 0; i < 2; ++i)
                a[i] = lds8(As, w * 32 + i * 16 + half, ks8 + quad);
#pragma unroll
            for (int j = 0; j < 8; ++j)
                b[j] = lds8(Bs, j * 16 + half, ks8 + quad);
#pragma unroll
            for (int i = 0; i < 2; ++i)
#pragma unroll
                for (int j = 0; j < 8; ++j)
                    acc[i][j] = __builtin_amdgcn_mfma_f32_16x16x32_bf16(a[i], b[j], acc[i][j], 0, 0, 0);
        }
        __syncthreads();
    }
    const int quad = lid >> 4, nl = lid & 15;
#pragma unroll
    for (int i = 0; i < 2; ++i)
#pragma unroll
        for (int j = 0; j < 8; ++j) {
            int n = j * 16 + nl;
            int t = mb * 128 + w * 32 + i * 16 + quad * 4;
            float* dst = Gpart + ((size_t)s * T_TOK + t) * ER + n;
#pragma unroll
            for (int r = 0; r < 4; ++r) dst[(size_t)r * ER] = acc[i][j][r];
        }
}

// ---------------- routing: top-2 softmax (fp32 logits), build U (vectorized) ----------------
__global__ __launch_bounds__(256) void route_u(const float* __restrict__ Gpart,
                                               const float* __restrict__ Lg,
                                               u16* __restrict__ U) {
    __shared__ float wmap[16][9];
    const int t0 = blockIdx.x * 16;
    const int tid = threadIdx.x;
    if (tid < 16) {
        float l[8];
#pragma unroll
        for (int e = 0; e < 8; ++e) l[e] = Lg[(t0 + tid) * 8 + e];
        int e1 = 0; float b1 = l[0];
#pragma unroll
        for (int e = 1; e < 8; ++e) if (l[e] > b1) { b1 = l[e]; e1 = e; }
        int e2 = -1; float b2 = -3.4e38f;
#pragma unroll
        for (int e = 0; e < 8; ++e) if (e != e1 && l[e] > b2) { b2 = l[e]; e2 = e; }
        float ex = __expf(b2 - b1);
        float inv = 1.f / (1.f + ex);
#pragma unroll
        for (int e = 0; e < 8; ++e) wmap[tid][e] = 0.f;
        wmap[tid][e1] = inv;
        wmap[tid][e2] = ex * inv;
    }
    __syncthreads();
#pragma unroll
    for (int it = 0; it < 2; ++it) {
        int idx = it * 256 + tid;          // 16 tokens * 32 float4-cols
        int tl = idx >> 5, c4 = idx & 31;
        float4 s = {0.f, 0.f, 0.f, 0.f};
        for (int sp = 0; sp < SPLIT; ++sp) {
            float4 g = ((const float4*)(Gpart + ((size_t)sp * T_TOK + t0 + tl) * ER))[c4];
            s.x += g.x; s.y += g.y; s.z += g.z; s.w += g.w;
        }
        float wv = wmap[tl][c4 >> 2];
        ushort4 o = { f2b(s.x * wv), f2b(s.y * wv), f2b(s.z * wv), f2b(s.w * wv) };
        ((ushort4*)(U + (size_t)(t0 + tl) * ER))[c4] = o;
    }
}

// ---------------- GEMM2: out = [X|U] @ [W|Bs2]^T + bias, fp32 out ----------------
// 256x256 tile, 8 waves (2M x 4N), BK=64, counted-vmcnt pipeline.
// LDS (128 KiB dynamic): 2 buffers x { A_ks0 | A_ks1 | B_ks0 | B_ks1 } of 16 KB each.
//   Region layout: 256 rows x 32 cols bf16 (64 B rows), slot-swizzle
//   slot = grp ^ ((row>>1)&3) -> 2-way banks (free) on ds_read_b128.
// Per K-tile: 2 phases; each phase:
//   12x ds_read_b128 -> lgkmcnt(0) -> s_barrier  (buf region now dead)
//   -> issue 4x global_load_lds for tile t+2's same region (overwrite safe)
//   -> [phase 1 only] vmcnt(8): tile t+1 landed, t+2's 8 loads stay in flight -> s_barrier
//   -> setprio(1); 32 MFMA; setprio(0)
// K-tiles 0..63 = X/W (k0 = t*64); tiles 64..65 = U/Bs2 (LoRA tail, stride ER).
__global__ __launch_bounds__(512) void gemm2(const u16* __restrict__ X,
                                             const u16* __restrict__ W,
                                             const float* __restrict__ bbf,
                                             const u16* __restrict__ U,
                                             const u16* __restrict__ Bs2,
                                             float* __restrict__ out) {
    extern __shared__ __align__(16) char smem[];
    const int tid = threadIdx.x;
    const int l = tid & 63, w = tid >> 6;        // 8 waves
    const int wm = w & 1, wn = w >> 1;           // 2M x 4N wave grid

    // XCD-bijective swizzle: 256 wg = 8 xcd * 32; each XCD gets 2 full M-rows.
    const int bid = blockIdx.x;
    const int sw = (bid & 7) * 32 + (bid >> 3);
    const int mb = sw >> 4, nb = sw & 15;

    // staging geometry (per-lane global source; LDS dest is wave-uniform + lane*16)
    const int srow = w * 16 + (l >> 2);                     // 0..127 within a 128-row round
    const int gcol = (((l & 3) ^ ((l >> 3) & 3)) << 3);     // swizzled col offset (elems)
    const int ldso = w * 1024;                              // wave-uniform LDS offset

    // frag-read geometry
    const int hl = l & 15;
    const int sgr = (((l >> 4) ^ ((hl >> 1) & 3)) << 4);    // swizzled 16B slot
    const int rbA = (wm * 128 + hl) * 64 + sgr;
    const int rbB = (wn * 64 + hl) * 64 + sgr;

    const u16* xrow = X   + (size_t)(mb * 256 + srow) * DIN;
    const u16* wrw  = W   + (size_t)(nb * 256 + srow) * DIN;
    const u16* urow = U   + (size_t)(mb * 256 + srow) * ER;
    const u16* brow = Bs2 + (size_t)(nb * 256 + srow) * ER;

    f32x4 acc[8][4];
#pragma unroll
    for (int i = 0; i < 8; ++i)
#pragma unroll
        for (int j = 0; j < 4; ++j) acc[i][j] = (f32x4){0.f, 0.f, 0.f, 0.f};

    auto stage = [&](int c, int ks, int t2) {
        char* dst = smem + (c << 16) + (ks << 14) + ldso;
        if (t2 < 64) {
            const int col = t2 * 64 + ks * 32 + gcol;
            async16(dst,         xrow + col);
            async16(dst + 8192,  xrow + (size_t)128 * DIN + col);
            async16(dst + 32768, wrw + col);
            async16(dst + 40960, wrw + (size_t)128 * DIN + col);
        } else {
            const int col = (t2 - 64) * 64 + ks * 32 + gcol;
            async16(dst,         urow + col);
            async16(dst + 8192,  urow + 128 * ER + col);
            async16(dst + 32768, brow + col);
            async16(dst + 40960, brow + 128 * ER + col);
        }
    };

    // prologue: tiles 0 and 1 fully staged; wait tile 0 (8 newest stay in flight)
    stage(0, 0, 0); stage(0, 1, 0);
    stage(1, 0, 1); stage(1, 1, 1);
    WAITV(8);
    RAW_BAR();

#pragma unroll 2
    for (int t = 0; t < 66; ++t) {
        const int c = t & 1;
        const char* seg = smem + (c << 16);
        // ---- phase ks=0
        {
            bf16x8 a[8], b[4];
#pragma unroll
            for (int i = 0; i < 8; ++i) a[i] = *(const bf16x8*)(seg + rbA + i * 1024);
#pragma unroll
            for (int j = 0; j < 4; ++j) b[j] = *(const bf16x8*)(seg + 32768 + rbB + j * 1024);
            LGKM0();                 // frags in regs -> region dead for all lanes of this wave
            RAW_BAR();               // ... and for all waves
            if (t + 2 < 66) stage(c, 0, t + 2);
            __builtin_amdgcn_s_setprio(1);
#pragma unroll
            for (int i = 0; i < 8; ++i)
#pragma unroll
                for (int j = 0; j < 4; ++j)
                    acc[i][j] = __builtin_amdgcn_mfma_f32_16x16x32_bf16(a[i], b[j], acc[i][j], 0, 0, 0);
            __builtin_amdgcn_s_setprio(0);
        }
        // ---- phase ks=1
        {
            const char* seg1 = seg + 16384;
            bf16x8 a[8], b[4];
#pragma unroll
            for (int i = 0; i < 8; ++i) a[i] = *(const bf16x8*)(seg1 + rbA + i * 1024);
#pragma unroll
            for (int j = 0; j < 4; ++j) b[j] = *(const bf16x8*)(seg1 + 32768 + rbB + j * 1024);
            LGKM0();
            RAW_BAR();
            if (t + 2 < 66) stage(c, 1, t + 2);
            if (t < 64) { WAITV(8); } else { WAITV(0); }   // t+1 landed; t+2 in flight
            RAW_BAR();
            __builtin_amdgcn_s_setprio(1);
#pragma unroll
            for (int i = 0; i < 8; ++i)
#pragma unroll
                for (int j = 0; j < 4; ++j)
                    acc[i][j] = __builtin_amdgcn_mfma_f32_16x16x32_bf16(a[i], b[j], acc[i][j], 0, 0, 0);
            __builtin_amdgcn_s_setprio(0);
        }
    }

    const int quad = l >> 4;
#pragma unroll
    for (int j = 0; j < 4; ++j) {
        const int n = nb * 256 + wn * 64 + j * 16 + hl;
        const float bz = bbf[n];
#pragma unroll
        for (int i = 0; i < 8; ++i) {
            const int m = mb * 256 + wm * 128 + i * 16 + quad * 4;
            float* dst = out + (size_t)m * DOUT + n;
#pragma unroll
            for (int r = 0; r < 4; ++r)
                dst[(size_t)r * DOUT] = acc[i][j][r] + bz;
        }
    }
}

extern "C" void kernel_launch(void* const* d_in, const int* in_sizes, int n_in,
                              void* d_out, int out_size, void* d_ws, size_t ws_size,
                              hipStream_t stream) {
    const float* x      = (const float*)d_in[0];
    const float* gate_w = (const float*)d_in[1];
    const float* base_w = (const float*)d_in[2];
    const float* base_b = (const float*)d_in[3];
    const float* lora_A = (const float*)d_in[4];
    const float* lora_B = (const float*)d_in[5];
    float* out = (float*)d_out;

    char* ws = (char*)d_ws;
    u16*   xb    = (u16*)(ws + OFF_XB);
    u16*   wb    = (u16*)(ws + OFF_WB);
    u16*   ab    = (u16*)(ws + OFF_AB);
    u16*   bs2   = (u16*)(ws + OFF_BS2);
    u16*   U     = (u16*)(ws + OFF_U);
    float* bbf   = (float*)(ws + OFF_BBF);
    float* Lg    = (float*)(ws + OFF_LG);
    float* Gpart = (float*)(ws + OFF_GPART);

    static bool attr_done = false;
    if (!attr_done) {
        (void)hipFuncSetAttribute(reinterpret_cast<const void*>(gemm2),
                                  hipFuncAttributeMaxDynamicSharedMemorySize, 131072);
        attr_done = true;
    }

    convert_big<<<16384, 256, 0, stream>>>(x, base_w, (uint4*)xb, (uint4*)wb);
    pack_small<<<4112, 256, 0, stream>>>(lora_A, lora_B, base_b, ab, bs2, bbf);
    gate_logits<<<T_TOK / 16, 256, 0, stream>>>(x, gate_w, Lg);
    gemm1<<<dim3(32, SPLIT), 256, 0, stream>>>(xb, ab, Gpart);
    route_u<<<T_TOK / 16, 256, 0, stream>>>(Gpart, Lg, U);
    gemm2<<<256, 512, 131072, stream>>>(xb, wb, bbf, U, bs2, out);
}

// Round 3
// 349.281 us; speedup vs baseline: 1.5320x; 1.5320x over previous
//
#include <hip/hip_runtime.h>
#include <hip/hip_bf16.h>

typedef unsigned short u16;
typedef __bf16  bf16x8 __attribute__((ext_vector_type(8)));
typedef float   f32x4  __attribute__((ext_vector_type(4)));

#define T_TOK 4096   // B*S tokens
#define DIN   4096
#define DOUT  4096
#define NEXP  8
#define ER    128    // E*R
#define SPLIT 8
#define KCH   (DIN / SPLIT)   // 512

// ws layout (bytes)
#define OFF_XB    0u           // bf16 x            33,554,432
#define OFF_WB    33554432u    // bf16 base_w       33,554,432
#define OFF_AB    67108864u    // bf16 lora_A flat   1,048,576
#define OFF_BS2   68157440u    // bf16 2*lora_B^T    1,048,576
#define OFF_U     69206016u    // bf16 U             1,048,576
#define OFF_BBF   70254592u    // fp32 bias             16,384
#define OFF_LG    70270976u    // fp32 logits          131,072
#define OFF_GPART 70402048u    // fp32 partials     16,777,216  -> end 87,179,264

__device__ __forceinline__ void async16(void* lds, const void* g) {
    __builtin_amdgcn_global_load_lds(
        (const __attribute__((address_space(1))) void*)g,
        (__attribute__((address_space(3))) void*)lds,
        16, 0, 0);
}

static __device__ __forceinline__ u16 f2b(float f) {
    __hip_bfloat16 h = __float2bfloat16(f);
    return *(u16*)&h;
}

// XOR-swizzled LDS read (128B rows, used by gemm1): slot (row, g') holds global
// column-group g'^ (row&7).
__device__ __forceinline__ bf16x8 lds8(const u16* base, int row, int grp) {
    return *(const bf16x8*)((const char*)base + row * 128 + (((grp ^ row) & 7) * 16));
}

// scheduling / sync primitives for the counted-vmcnt pipeline
#define FENCE() asm volatile("" ::: "memory")
#define RAW_BAR() do { FENCE(); __builtin_amdgcn_s_barrier(); FENCE(); } while (0)
#define LGKM0() do { asm volatile("s_waitcnt lgkmcnt(0)" ::: "memory"); \
                     __builtin_amdgcn_sched_barrier(0); } while (0)
#define WAITV(N) do { asm volatile("s_waitcnt vmcnt(" #N ")" ::: "memory"); \
                      __builtin_amdgcn_sched_barrier(0); } while (0)

// ---------------- convert fp32 -> bf16: x and base_w (8 elems/thread)
__global__ __launch_bounds__(256) void convert_big(const float* __restrict__ x,
                                                   const float* __restrict__ w,
                                                   uint4* __restrict__ xb,
                                                   uint4* __restrict__ wb) {
    int gid = blockIdx.x * 256 + threadIdx.x;          // 2 * 2,097,152 threads
    const float4* s = (const float4*)((gid < 2097152) ? x : w);
    uint4* dst      = (gid < 2097152) ? xb : wb;
    int li = gid & 2097151;
    float4 a = s[2 * li], b = s[2 * li + 1];
    uint4 o;
    o.x = (unsigned)f2b(a.x) | ((unsigned)f2b(a.y) << 16);
    o.y = (unsigned)f2b(a.z) | ((unsigned)f2b(a.w) << 16);
    o.z = (unsigned)f2b(b.x) | ((unsigned)f2b(b.y) << 16);
    o.w = (unsigned)f2b(b.z) | ((unsigned)f2b(b.w) << 16);
    dst[li] = o;
}

// ---------------- small packs: lora_A (bf16), 2*lora_B^T (bf16), bias (fp32)
__global__ __launch_bounds__(256) void pack_small(const float* __restrict__ lora_A,
                                                  const float* __restrict__ lora_B,
                                                  const float* __restrict__ base_b,
                                                  u16* __restrict__ ab,
                                                  u16* __restrict__ bs2,
                                                  float* __restrict__ bbf) {
    int idx = blockIdx.x * 256 + threadIdx.x;   // total 1,052,672
    if (idx < 524288) {                          // lora_A flat copy [e*16+r][d]
        ab[idx] = f2b(lora_A[idx]);
    } else if (idx < 1048576) {                  // bs2[o, e*16+r] = 2*lora_B[e,o,r]
        int j = idx - 524288;
        int o = j >> 7, c = j & 127, e = c >> 4, r = c & 15;
        bs2[j] = f2b(lora_B[(e * DOUT + o) * 16 + r] * 2.0f);
    } else if (idx < 1052672) {
        int j = idx - 1048576;
        bbf[j] = base_b[j];
    }
}

// ---------------- fp32 gate logits: 4 tokens per wave (gate_w load reuse) ----------------
__global__ __launch_bounds__(256) void gate_logits(const float* __restrict__ x,
                                                   const float* __restrict__ gw,
                                                   float* __restrict__ Lg) {
    const int w = threadIdx.x >> 6, lid = threadIdx.x & 63;
    const int t0 = (blockIdx.x * 4 + w) * 4;
    float acc[4][8];
#pragma unroll
    for (int j = 0; j < 4; ++j)
#pragma unroll
        for (int e = 0; e < 8; ++e) acc[j][e] = 0.f;
    for (int i = lid; i < DIN / 4; i += 64) {
        float4 gv[8];
#pragma unroll
        for (int e = 0; e < 8; ++e)
            gv[e] = ((const float4*)(gw + (size_t)e * DIN))[i];
#pragma unroll
        for (int j = 0; j < 4; ++j) {
            float4 xv = ((const float4*)(x + (size_t)(t0 + j) * DIN))[i];
#pragma unroll
            for (int e = 0; e < 8; ++e)
                acc[j][e] += xv.x * gv[e].x + xv.y * gv[e].y + xv.z * gv[e].z + xv.w * gv[e].w;
        }
    }
#pragma unroll
    for (int j = 0; j < 4; ++j)
#pragma unroll
        for (int e = 0; e < 8; ++e) {
            float v = acc[j][e];
            for (int off = 32; off; off >>= 1) v += __shfl_down(v, off, 64);
            if (lid == 0) Lg[(t0 + j) * 8 + e] = v;
        }
}

// ---------------- GEMM1: Gpart[s] = X @ lora_A^T, split-K fp32 partials
// grid (32 mb, 8 split), block 256. Tile 128(M) x 128(N) x 64(K).
__global__ __launch_bounds__(256) void gemm1(const u16* __restrict__ X,
                                             const u16* __restrict__ ab,
                                             float* __restrict__ Gpart) {
    __shared__ __align__(16) u16 As[128 * 64];
    __shared__ __align__(16) u16 Bs[128 * 64];
    const int mb = blockIdx.x, s = blockIdx.y;
    const int w = threadIdx.x >> 6, lid = threadIdx.x & 63;
    const int lrow = lid >> 3;                    // row within 8-row chunk
    const int lcolb = ((lid & 7) ^ lrow) * 16;    // swizzled source column group

    f32x4 acc[2][8];
#pragma unroll
    for (int i = 0; i < 2; ++i)
#pragma unroll
        for (int j = 0; j < 8; ++j) acc[i][j] = (f32x4){0.f, 0.f, 0.f, 0.f};

    int k0 = s * KCH;
    for (int kt = 0; kt < KCH / 64; ++kt, k0 += 64) {
#pragma unroll
        for (int q = 0; q < 4; ++q) {
            int c = w * 4 + q;
            int arow = mb * 128 + c * 8 + lrow;
            async16((char*)As + c * 1024,
                    (const char*)X + ((size_t)arow * DIN + k0) * 2 + lcolb);
            async16((char*)Bs + c * 1024,
                    (const char*)ab + ((size_t)(c * 8 + lrow) * DIN + k0) * 2 + lcolb);
        }
        __syncthreads();
        const int quad = lid >> 4, half = lid & 15;
#pragma unroll
        for (int ks8 = 0; ks8 < 8; ks8 += 4) {
            bf16x8 a[2], b[8];
#pragma unroll
            for (int i = 0; i < 2; ++i)
                a[i] = lds8(As, w * 32 + i * 16 + half, ks8 + quad);
#pragma unroll
            for (int j = 0; j < 8; ++j)
                b[j] = lds8(Bs, j * 16 + half, ks8 + quad);
#pragma unroll
            for (int i = 0; i < 2; ++i)
#pragma unroll
                for (int j = 0; j < 8; ++j)
                    acc[i][j] = __builtin_amdgcn_mfma_f32_16x16x32_bf16(a[i], b[j], acc[i][j], 0, 0, 0);
        }
        __syncthreads();
    }
    const int quad = lid >> 4, nl = lid & 15;
#pragma unroll
    for (int i = 0; i < 2; ++i)
#pragma unroll
        for (int j = 0; j < 8; ++j) {
            int n = j * 16 + nl;
            int t = mb * 128 + w * 32 + i * 16 + quad * 4;
            float* dst = Gpart + ((size_t)s * T_TOK + t) * ER + n;
#pragma unroll
            for (int r = 0; r < 4; ++r) dst[(size_t)r * ER] = acc[i][j][r];
        }
}

// ---------------- routing: top-2 softmax (fp32 logits), build U (vectorized) ----------------
__global__ __launch_bounds__(256) void route_u(const float* __restrict__ Gpart,
                                               const float* __restrict__ Lg,
                                               u16* __restrict__ U) {
    __shared__ float wmap[16][9];
    const int t0 = blockIdx.x * 16;
    const int tid = threadIdx.x;
    if (tid < 16) {
        float l[8];
#pragma unroll
        for (int e = 0; e < 8; ++e) l[e] = Lg[(t0 + tid) * 8 + e];
        int e1 = 0; float b1 = l[0];
#pragma unroll
        for (int e = 1; e < 8; ++e) if (l[e] > b1) { b1 = l[e]; e1 = e; }
        int e2 = -1; float b2 = -3.4e38f;
#pragma unroll
        for (int e = 0; e < 8; ++e) if (e != e1 && l[e] > b2) { b2 = l[e]; e2 = e; }
        float ex = __expf(b2 - b1);
        float inv = 1.f / (1.f + ex);
#pragma unroll
        for (int e = 0; e < 8; ++e) wmap[tid][e] = 0.f;
        wmap[tid][e1] = inv;
        wmap[tid][e2] = ex * inv;
    }
    __syncthreads();
#pragma unroll
    for (int it = 0; it < 2; ++it) {
        int idx = it * 256 + tid;          // 16 tokens * 32 float4-cols
        int tl = idx >> 5, c4 = idx & 31;
        float4 s = {0.f, 0.f, 0.f, 0.f};
        for (int sp = 0; sp < SPLIT; ++sp) {
            float4 g = ((const float4*)(Gpart + ((size_t)sp * T_TOK + t0 + tl) * ER))[c4];
            s.x += g.x; s.y += g.y; s.z += g.z; s.w += g.w;
        }
        float wv = wmap[tl][c4 >> 2];
        ushort4 o = { f2b(s.x * wv), f2b(s.y * wv), f2b(s.z * wv), f2b(s.w * wv) };
        ((ushort4*)(U + (size_t)(t0 + tl) * ER))[c4] = o;
    }
}

// ---------------- GEMM2: out = [X|U] @ [W|Bs2]^T + bias, fp32 out ----------------
// 256x256 tile, 8 waves (2M x 4N), BK=64. m201-style 4-phase/K-tile schedule.
// LDS (128 KiB dynamic): 2 dbufs x { A_ks0 | A_ks1 | B_ks0 | B_ks1 }, 16 KB each
//   (region = 256 rows x 32 cols bf16, 64 B rows; slot s of row r holds global
//    col-group s ^ ((r>>1)&3) -> 2-way banks (free) on ds_read_b128).
// Phase = { ds_read frags ; stage 1 region (2 loads/thr) ; [WAITV] ; barrier ;
//           lgkmcnt(0) ; setprio(1) 16 MFMA setprio(0) ; barrier }.
// Stage plan at tile t: P0->A1(t+1), P1->B1(t+1), P2->A0(t+2), P3->B0(t+2).
// Race proof: a staged region's previous readers issued+consumed their ds_reads
// before that phase's trailing barrier, which precedes the stage issue.
// Counted vmcnt(8) at P1 & P3 only (2 loads/thr/phase, 4 batches in flight);
// wind-down: t=64 P3 -> vmcnt(4); t=65 P1 -> vmcnt(0).
__global__ __launch_bounds__(512) void gemm2(const u16* __restrict__ X,
                                             const u16* __restrict__ W,
                                             const float* __restrict__ bbf,
                                             const u16* __restrict__ U,
                                             const u16* __restrict__ Bs2,
                                             float* __restrict__ out) {
    extern __shared__ __align__(16) char smem[];
    const int tid = threadIdx.x;
    const int l = tid & 63, w = tid >> 6;        // 8 waves
    const int wm = w & 1, wn = w >> 1;           // 2M x 4N wave grid

    // XCD-bijective swizzle: 256 wg = 8 xcd * 32.
    const int bid = blockIdx.x;
    const int sw = (bid & 7) * 32 + (bid >> 3);
    const int mb = sw >> 4, nb = sw & 15;

    // staging geometry (per-lane global source; LDS dest = wave-uniform + lane*16)
    const int srow = w * 16 + (l >> 2);                     // 0..127 per round
    const int gcol = (((l & 3) ^ ((l >> 3) & 3)) << 3);     // pre-swizzled col (elems)
    const int ldso = w * 1024;                              // wave-uniform LDS offset

    // frag-read geometry
    const int hl = l & 15, quad = l >> 4;
    const int sgr = ((quad ^ ((hl >> 1) & 3)) << 4);        // swizzled 16B slot
    const int rbA = (wm * 128 + hl) * 64 + sgr;
    const int rbB = (wn * 64 + hl) * 64 + sgr;

    const u16* xrow = X   + (size_t)(mb * 256 + srow) * DIN;
    const u16* wrw  = W   + (size_t)(nb * 256 + srow) * DIN;
    const u16* urow = U   + (size_t)(mb * 256 + srow) * ER;
    const u16* brow = Bs2 + (size_t)(nb * 256 + srow) * ER;

    f32x4 acc[8][4];
#pragma unroll
    for (int i = 0; i < 8; ++i)
#pragma unroll
        for (int j = 0; j < 4; ++j) acc[i][j] = (f32x4){0.f, 0.f, 0.f, 0.f};

    // stage one 16 KB region (2 loads/thread). t2 selects dbuf via parity.
    auto stageA = [&](int t2, int ks) {
        char* dst = smem + ((t2 & 1) << 16) + (ks << 14) + ldso;
        if (t2 < 64) {
            const int col = t2 * 64 + ks * 32 + gcol;
            async16(dst,        xrow + col);
            async16(dst + 8192, xrow + (size_t)128 * DIN + col);
        } else {
            const int col = (t2 - 64) * 64 + ks * 32 + gcol;
            async16(dst,        urow + col);
            async16(dst + 8192, urow + 128 * ER + col);
        }
    };
    auto stageB = [&](int t2, int ks) {
        char* dst = smem + ((t2 & 1) << 16) + 32768 + (ks << 14) + ldso;
        if (t2 < 64) {
            const int col = t2 * 64 + ks * 32 + gcol;
            async16(dst,        wrw + col);
            async16(dst + 8192, wrw + (size_t)128 * DIN + col);
        } else {
            const int col = (t2 - 64) * 64 + ks * 32 + gcol;
            async16(dst,        brow + col);
            async16(dst + 8192, brow + 128 * ER + col);
        }
    };

    bf16x8 bfr[4];   // b-frags held across each phase pair (read once per k-slice)

    // PHASE: template order — reads, stage, [waitv], barrier, lgkm0, MFMA, barrier.
#define PHASE(SEG, KS, IB, READB, STAGE, WV) do {                              \
        const char* rs_ = (SEG) + ((KS) << 14);                                \
        bf16x8 a_[4];                                                          \
        _Pragma("unroll")                                                      \
        for (int i_ = 0; i_ < 4; ++i_)                                         \
            a_[i_] = *(const bf16x8*)(rs_ + rbA + ((IB) + i_) * 1024);         \
        if (READB) {                                                           \
            _Pragma("unroll")                                                  \
            for (int j_ = 0; j_ < 4; ++j_)                                     \
                bfr[j_] = *(const bf16x8*)(rs_ + 32768 + rbB + j_ * 1024);     \
        }                                                                      \
        STAGE;                                                                 \
        WV;                                                                    \
        RAW_BAR();                                                             \
        LGKM0();                                                               \
        __builtin_amdgcn_s_setprio(1);                                         \
        _Pragma("unroll")                                                      \
        for (int i_ = 0; i_ < 4; ++i_)                                         \
            _Pragma("unroll")                                                  \
            for (int j_ = 0; j_ < 4; ++j_)                                     \
                acc[(IB) + i_][j_] = __builtin_amdgcn_mfma_f32_16x16x32_bf16(  \
                    a_[i_], bfr[j_], acc[(IB) + i_][j_], 0, 0, 0);             \
        __builtin_amdgcn_s_setprio(0);                                         \
        RAW_BAR();                                                             \
    } while (0)

    // prologue: tile0 all 4 regions + tile1 A0,B0 (12 loads); oldest 4 (=tile0
    // A0,B0) must land before P0(0): allow newest 8.
    stageA(0, 0); stageB(0, 0); stageA(0, 1); stageB(0, 1);
    stageA(1, 0); stageB(1, 0);
    WAITV(8);
    RAW_BAR();

#pragma unroll 1
    for (int t = 0; t < 64; ++t) {
        const char* seg = smem + ((t & 1) << 16);
        PHASE(seg, 0, 0, true,  { stageA(t + 1, 1); }, {});            // P0
        PHASE(seg, 0, 4, false, { stageB(t + 1, 1); }, { WAITV(8); }); // P1
        PHASE(seg, 1, 0, true,  { stageA(t + 2, 0); }, {});            // P2
        PHASE(seg, 1, 4, false, { stageB(t + 2, 0); }, { WAITV(8); }); // P3
    }
    // tile 64 (dbuf 0): stage only A1(65), B1(65)
    {
        const char* seg = smem;
        PHASE(seg, 0, 0, true,  { stageA(65, 1); }, {});
        PHASE(seg, 0, 4, false, { stageB(65, 1); }, { WAITV(8); });
        PHASE(seg, 1, 0, true,  {}, {});
        PHASE(seg, 1, 4, false, {}, { WAITV(4); });
    }
    // tile 65 (dbuf 1): drain
    {
        const char* seg = smem + 65536;
        PHASE(seg, 0, 0, true,  {}, {});
        PHASE(seg, 0, 4, false, {}, { WAITV(0); });
        PHASE(seg, 1, 0, true,  {}, {});
        PHASE(seg, 1, 4, false, {}, {});
    }
#undef PHASE

    const int nl = hl;
#pragma unroll
    for (int j = 0; j < 4; ++j) {
        const int n = nb * 256 + wn * 64 + j * 16 + nl;
        const float bz = bbf[n];
#pragma unroll
        for (int i = 0; i < 8; ++i) {
            const int m = mb * 256 + wm * 128 + i * 16 + quad * 4;
            float* dst = out + (size_t)m * DOUT + n;
#pragma unroll
            for (int r = 0; r < 4; ++r)
                dst[(size_t)r * DOUT] = acc[i][j][r] + bz;
        }
    }
}

extern "C" void kernel_launch(void* const* d_in, const int* in_sizes, int n_in,
                              void* d_out, int out_size, void* d_ws, size_t ws_size,
                              hipStream_t stream) {
    const float* x      = (const float*)d_in[0];
    const float* gate_w = (const float*)d_in[1];
    const float* base_w = (const float*)d_in[2];
    const float* base_b = (const float*)d_in[3];
    const float* lora_A = (const float*)d_in[4];
    const float* lora_B = (const float*)d_in[5];
    float* out = (float*)d_out;

    char* ws = (char*)d_ws;
    u16*   xb    = (u16*)(ws + OFF_XB);
    u16*   wb    = (u16*)(ws + OFF_WB);
    u16*   ab    = (u16*)(ws + OFF_AB);
    u16*   bs2   = (u16*)(ws + OFF_BS2);
    u16*   U     = (u16*)(ws + OFF_U);
    float* bbf   = (float*)(ws + OFF_BBF);
    float* Lg    = (float*)(ws + OFF_LG);
    float* Gpart = (float*)(ws + OFF_GPART);

    static bool attr_done = false;
    if (!attr_done) {
        (void)hipFuncSetAttribute(reinterpret_cast<const void*>(gemm2),
                                  hipFuncAttributeMaxDynamicSharedMemorySize, 131072);
        attr_done = true;
    }

    convert_big<<<16384, 256, 0, stream>>>(x, base_w, (uint4*)xb, (uint4*)wb);
    pack_small<<<4112, 256, 0, stream>>>(lora_A, lora_B, base_b, ab, bs2, bbf);
    gate_logits<<<T_TOK / 16, 256, 0, stream>>>(x, gate_w, Lg);
    gemm1<<<dim3(32, SPLIT), 256, 0, stream>>>(xb, ab, Gpart);
    route_u<<<T_TOK / 16, 256, 0, stream>>>(Gpart, Lg, U);
    gemm2<<<256, 512, 131072, stream>>>(xb, wb, bbf, U, bs2, out);
}

// Round 4
// 334.166 us; speedup vs baseline: 1.6013x; 1.0452x over previous
//
#include <hip/hip_runtime.h>
#include <hip/hip_bf16.h>

typedef unsigned short u16;
typedef __bf16  bf16x8 __attribute__((ext_vector_type(8)));
typedef float   f32x4  __attribute__((ext_vector_type(4)));

#define T_TOK 4096   // B*S tokens
#define DIN   4096
#define DOUT  4096
#define NEXP  8
#define ER    128    // E*R
#define SPLIT 8
#define KCH   (DIN / SPLIT)   // 512

// ws layout (bytes)
#define OFF_XB    0u           // bf16 x            33,554,432
#define OFF_WB    33554432u    // bf16 base_w       33,554,432
#define OFF_AB    67108864u    // bf16 lora_A flat   1,048,576
#define OFF_BS2   68157440u    // bf16 2*lora_B^T    1,048,576
#define OFF_U     69206016u    // bf16 U             1,048,576
#define OFF_BBF   70254592u    // fp32 bias             16,384
#define OFF_LG    70270976u    // fp32 logits          131,072
#define OFF_GPART 70402048u    // fp32 partials     16,777,216  -> end 87,179,264

__device__ __forceinline__ void async16(void* lds, const void* g) {
    __builtin_amdgcn_global_load_lds(
        (const __attribute__((address_space(1))) void*)g,
        (__attribute__((address_space(3))) void*)lds,
        16, 0, 0);
}

static __device__ __forceinline__ u16 f2b(float f) {
    __hip_bfloat16 h = __float2bfloat16(f);
    return *(u16*)&h;
}

// XOR-swizzled LDS read (128B rows, used by gemm1): slot (row, g') holds global
// column-group g'^ (row&7).
__device__ __forceinline__ bf16x8 lds8(const u16* base, int row, int grp) {
    return *(const bf16x8*)((const char*)base + row * 128 + (((grp ^ row) & 7) * 16));
}

// scheduling / sync primitives for the counted-vmcnt pipeline
#define FENCE() asm volatile("" ::: "memory")
#define RAW_BAR() do { FENCE(); __builtin_amdgcn_s_barrier(); FENCE(); } while (0)
#define LGKM0() do { asm volatile("s_waitcnt lgkmcnt(0)" ::: "memory"); \
                     __builtin_amdgcn_sched_barrier(0); } while (0)
#define WAITV(N) do { asm volatile("s_waitcnt vmcnt(" #N ")" ::: "memory"); \
                      __builtin_amdgcn_sched_barrier(0); } while (0)

// ---------------- prep_x: single pass over x (fp32) -> xb (bf16) + gate logits.
// Fuses old convert_big's x-half and gate_logits: x streamed ONCE instead of twice.
// grid 256 blocks x 256 thr; wave w handles tokens t0..t0+3 (gate_w reuse x4).
__global__ __launch_bounds__(256) void prep_x(const float* __restrict__ x,
                                              const float* __restrict__ gw,
                                              u16* __restrict__ xb,
                                              float* __restrict__ Lg) {
    const int w = threadIdx.x >> 6, lid = threadIdx.x & 63;
    const int t0 = (blockIdx.x * 4 + w) * 4;
    float acc[4][8];
#pragma unroll
    for (int j = 0; j < 4; ++j)
#pragma unroll
        for (int e = 0; e < 8; ++e) acc[j][e] = 0.f;
    for (int i = lid; i < DIN / 4; i += 64) {
        float4 gv[8];
#pragma unroll
        for (int e = 0; e < 8; ++e)
            gv[e] = ((const float4*)(gw + (size_t)e * DIN))[i];
#pragma unroll
        for (int j = 0; j < 4; ++j) {
            float4 xv = ((const float4*)(x + (size_t)(t0 + j) * DIN))[i];
            ushort4 o = { f2b(xv.x), f2b(xv.y), f2b(xv.z), f2b(xv.w) };
            ((ushort4*)(xb + (size_t)(t0 + j) * DIN))[i] = o;
#pragma unroll
            for (int e = 0; e < 8; ++e)
                acc[j][e] += xv.x * gv[e].x + xv.y * gv[e].y + xv.z * gv[e].z + xv.w * gv[e].w;
        }
    }
#pragma unroll
    for (int j = 0; j < 4; ++j)
#pragma unroll
        for (int e = 0; e < 8; ++e) {
            float v = acc[j][e];
            for (int off = 32; off; off >>= 1) v += __shfl_down(v, off, 64);
            if (lid == 0) Lg[(t0 + j) * 8 + e] = v;
        }
}

// ---------------- convert_w_pack: base_w fp32->bf16 (blocks 0..8191) +
// small packs lora_A/lora_B^T/bias (blocks 8192..12303). One launch.
__global__ __launch_bounds__(256) void convert_w_pack(const float* __restrict__ wsrc,
                                                      const float* __restrict__ lora_A,
                                                      const float* __restrict__ lora_B,
                                                      const float* __restrict__ base_b,
                                                      uint4* __restrict__ wb,
                                                      u16* __restrict__ ab,
                                                      u16* __restrict__ bs2,
                                                      float* __restrict__ bbf) {
    const int bid = blockIdx.x;
    if (bid < 8192) {
        int li = bid * 256 + threadIdx.x;        // 2,097,152 threads for 4096x4096
        const float4* s = (const float4*)wsrc;
        float4 a = s[2 * li], b = s[2 * li + 1];
        uint4 o;
        o.x = (unsigned)f2b(a.x) | ((unsigned)f2b(a.y) << 16);
        o.y = (unsigned)f2b(a.z) | ((unsigned)f2b(a.w) << 16);
        o.z = (unsigned)f2b(b.x) | ((unsigned)f2b(b.y) << 16);
        o.w = (unsigned)f2b(b.z) | ((unsigned)f2b(b.w) << 16);
        wb[li] = o;
    } else {
        int idx = (bid - 8192) * 256 + threadIdx.x;   // total 1,052,672
        if (idx < 524288) {                          // lora_A flat copy [e*16+r][d]
            ab[idx] = f2b(lora_A[idx]);
        } else if (idx < 1048576) {                  // bs2[o, e*16+r] = 2*lora_B[e,o,r]
            int j = idx - 524288;
            int o = j >> 7, c = j & 127, e = c >> 4, r = c & 15;
            bs2[j] = f2b(lora_B[(e * DOUT + o) * 16 + r] * 2.0f);
        } else if (idx < 1052672) {
            int j = idx - 1048576;
            bbf[j] = base_b[j];
        }
    }
}

// ---------------- GEMM1: Gpart[s] = X @ lora_A^T, split-K fp32 partials
// grid (32 mb, 8 split), block 256. Tile 128(M) x 128(N) x 64(K).
__global__ __launch_bounds__(256) void gemm1(const u16* __restrict__ X,
                                             const u16* __restrict__ ab,
                                             float* __restrict__ Gpart) {
    __shared__ __align__(16) u16 As[128 * 64];
    __shared__ __align__(16) u16 Bs[128 * 64];
    const int mb = blockIdx.x, s = blockIdx.y;
    const int w = threadIdx.x >> 6, lid = threadIdx.x & 63;
    const int lrow = lid >> 3;                    // row within 8-row chunk
    const int lcolb = ((lid & 7) ^ lrow) * 16;    // swizzled source column group

    f32x4 acc[2][8];
#pragma unroll
    for (int i = 0; i < 2; ++i)
#pragma unroll
        for (int j = 0; j < 8; ++j) acc[i][j] = (f32x4){0.f, 0.f, 0.f, 0.f};

    int k0 = s * KCH;
    for (int kt = 0; kt < KCH / 64; ++kt, k0 += 64) {
#pragma unroll
        for (int q = 0; q < 4; ++q) {
            int c = w * 4 + q;
            int arow = mb * 128 + c * 8 + lrow;
            async16((char*)As + c * 1024,
                    (const char*)X + ((size_t)arow * DIN + k0) * 2 + lcolb);
            async16((char*)Bs + c * 1024,
                    (const char*)ab + ((size_t)(c * 8 + lrow) * DIN + k0) * 2 + lcolb);
        }
        __syncthreads();
        const int quad = lid >> 4, half = lid & 15;
#pragma unroll
        for (int ks8 = 0; ks8 < 8; ks8 += 4) {
            bf16x8 a[2], b[8];
#pragma unroll
            for (int i = 0; i < 2; ++i)
                a[i] = lds8(As, w * 32 + i * 16 + half, ks8 + quad);
#pragma unroll
            for (int j = 0; j < 8; ++j)
                b[j] = lds8(Bs, j * 16 + half, ks8 + quad);
#pragma unroll
            for (int i = 0; i < 2; ++i)
#pragma unroll
                for (int j = 0; j < 8; ++j)
                    acc[i][j] = __builtin_amdgcn_mfma_f32_16x16x32_bf16(a[i], b[j], acc[i][j], 0, 0, 0);
        }
        __syncthreads();
    }
    const int quad = lid >> 4, nl = lid & 15;
#pragma unroll
    for (int i = 0; i < 2; ++i)
#pragma unroll
        for (int j = 0; j < 8; ++j) {
            int n = j * 16 + nl;
            int t = mb * 128 + w * 32 + i * 16 + quad * 4;
            float* dst = Gpart + ((size_t)s * T_TOK + t) * ER + n;
#pragma unroll
            for (int r = 0; r < 4; ++r) dst[(size_t)r * ER] = acc[i][j][r];
        }
}

// ---------------- routing: top-2 softmax (fp32 logits), build U (vectorized) ----------------
__global__ __launch_bounds__(256) void route_u(const float* __restrict__ Gpart,
                                               const float* __restrict__ Lg,
                                               u16* __restrict__ U) {
    __shared__ float wmap[16][9];
    const int t0 = blockIdx.x * 16;
    const int tid = threadIdx.x;
    if (tid < 16) {
        float l[8];
#pragma unroll
        for (int e = 0; e < 8; ++e) l[e] = Lg[(t0 + tid) * 8 + e];
        int e1 = 0; float b1 = l[0];
#pragma unroll
        for (int e = 1; e < 8; ++e) if (l[e] > b1) { b1 = l[e]; e1 = e; }
        int e2 = -1; float b2 = -3.4e38f;
#pragma unroll
        for (int e = 0; e < 8; ++e) if (e != e1 && l[e] > b2) { b2 = l[e]; e2 = e; }
        float ex = __expf(b2 - b1);
        float inv = 1.f / (1.f + ex);
#pragma unroll
        for (int e = 0; e < 8; ++e) wmap[tid][e] = 0.f;
        wmap[tid][e1] = inv;
        wmap[tid][e2] = ex * inv;
    }
    __syncthreads();
#pragma unroll
    for (int it = 0; it < 2; ++it) {
        int idx = it * 256 + tid;          // 16 tokens * 32 float4-cols
        int tl = idx >> 5, c4 = idx & 31;
        float4 s = {0.f, 0.f, 0.f, 0.f};
        for (int sp = 0; sp < SPLIT; ++sp) {
            float4 g = ((const float4*)(Gpart + ((size_t)sp * T_TOK + t0 + tl) * ER))[c4];
            s.x += g.x; s.y += g.y; s.z += g.z; s.w += g.w;
        }
        float wv = wmap[tl][c4 >> 2];
        ushort4 o = { f2b(s.x * wv), f2b(s.y * wv), f2b(s.z * wv), f2b(s.w * wv) };
        ((ushort4*)(U + (size_t)(t0 + tl) * ER))[c4] = o;
    }
}

// ---------------- GEMM2: out = [X|U] @ [W|Bs2]^T + bias, fp32 out ----------------
// 256x256 tile, 8 waves (2M x 4N), BK=64. m201-style 4-phase/K-tile schedule.
// LDS (128 KiB dynamic): 2 dbufs x { A_ks0 | A_ks1 | B_ks0 | B_ks1 }, 16 KB each
//   (region = 256 rows x 32 cols bf16, 64 B rows; slot s of row r holds global
//    col-group s ^ ((r>>1)&3) -> 2-way banks (free) on ds_read_b128).
// Phase = { ds_read frags ; stage 1 region (2 loads/thr) ; [WAITV] ; barrier ;
//           lgkmcnt(0) ; setprio(1) 16 MFMA setprio(0) ; barrier }.
// Stage plan at tile t: P0->A1(t+1), P1->B1(t+1), P2->A0(t+2), P3->B0(t+2).
// Race proof: a staged region's previous readers issued+consumed their ds_reads
// before that phase's trailing barrier, which precedes the stage issue.
// Counted vmcnt(8) at P1 & P3 only (2 loads/thr/phase, 4 batches in flight);
// wind-down: t=64 P3 -> vmcnt(4); t=65 P1 -> vmcnt(0).
__global__ __launch_bounds__(512) void gemm2(const u16* __restrict__ X,
                                             const u16* __restrict__ W,
                                             const float* __restrict__ bbf,
                                             const u16* __restrict__ U,
                                             const u16* __restrict__ Bs2,
                                             float* __restrict__ out) {
    extern __shared__ __align__(16) char smem[];
    const int tid = threadIdx.x;
    const int l = tid & 63, w = tid >> 6;        // 8 waves
    const int wm = w & 1, wn = w >> 1;           // 2M x 4N wave grid

    // XCD-bijective swizzle: 256 wg = 8 xcd * 32.
    const int bid = blockIdx.x;
    const int sw = (bid & 7) * 32 + (bid >> 3);
    const int mb = sw >> 4, nb = sw & 15;

    // staging geometry (per-lane global source; LDS dest = wave-uniform + lane*16)
    const int srow = w * 16 + (l >> 2);                     // 0..127 per round
    const int gcol = (((l & 3) ^ ((l >> 3) & 3)) << 3);     // pre-swizzled col (elems)
    const int ldso = w * 1024;                              // wave-uniform LDS offset

    // frag-read geometry
    const int hl = l & 15, quad = l >> 4;
    const int sgr = ((quad ^ ((hl >> 1) & 3)) << 4);        // swizzled 16B slot
    const int rbA = (wm * 128 + hl) * 64 + sgr;
    const int rbB = (wn * 64 + hl) * 64 + sgr;

    const u16* xrow = X   + (size_t)(mb * 256 + srow) * DIN;
    const u16* wrw  = W   + (size_t)(nb * 256 + srow) * DIN;
    const u16* urow = U   + (size_t)(mb * 256 + srow) * ER;
    const u16* brow = Bs2 + (size_t)(nb * 256 + srow) * ER;

    f32x4 acc[8][4];
#pragma unroll
    for (int i = 0; i < 8; ++i)
#pragma unroll
        for (int j = 0; j < 4; ++j) acc[i][j] = (f32x4){0.f, 0.f, 0.f, 0.f};

    // stage one 16 KB region (2 loads/thread). t2 selects dbuf via parity.
    auto stageA = [&](int t2, int ks) {
        char* dst = smem + ((t2 & 1) << 16) + (ks << 14) + ldso;
        if (t2 < 64) {
            const int col = t2 * 64 + ks * 32 + gcol;
            async16(dst,        xrow + col);
            async16(dst + 8192, xrow + (size_t)128 * DIN + col);
        } else {
            const int col = (t2 - 64) * 64 + ks * 32 + gcol;
            async16(dst,        urow + col);
            async16(dst + 8192, urow + 128 * ER + col);
        }
    };
    auto stageB = [&](int t2, int ks) {
        char* dst = smem + ((t2 & 1) << 16) + 32768 + (ks << 14) + ldso;
        if (t2 < 64) {
            const int col = t2 * 64 + ks * 32 + gcol;
            async16(dst,        wrw + col);
            async16(dst + 8192, wrw + (size_t)128 * DIN + col);
        } else {
            const int col = (t2 - 64) * 64 + ks * 32 + gcol;
            async16(dst,        brow + col);
            async16(dst + 8192, brow + 128 * ER + col);
        }
    };

    bf16x8 bfr[4];   // b-frags held across each phase pair (read once per k-slice)

    // PHASE: template order — reads, stage, [waitv], barrier, lgkm0, MFMA, barrier.
#define PHASE(SEG, KS, IB, READB, STAGE, WV) do {                              \
        const char* rs_ = (SEG) + ((KS) << 14);                                \
        bf16x8 a_[4];                                                          \
        _Pragma("unroll")                                                      \
        for (int i_ = 0; i_ < 4; ++i_)                                         \
            a_[i_] = *(const bf16x8*)(rs_ + rbA + ((IB) + i_) * 1024);         \
        if (READB) {                                                           \
            _Pragma("unroll")                                                  \
            for (int j_ = 0; j_ < 4; ++j_)                                     \
                bfr[j_] = *(const bf16x8*)(rs_ + 32768 + rbB + j_ * 1024);     \
        }                                                                      \
        STAGE;                                                                 \
        WV;                                                                    \
        RAW_BAR();                                                             \
        LGKM0();                                                               \
        __builtin_amdgcn_s_setprio(1);                                         \
        _Pragma("unroll")                                                      \
        for (int i_ = 0; i_ < 4; ++i_)                                         \
            _Pragma("unroll")                                                  \
            for (int j_ = 0; j_ < 4; ++j_)                                     \
                acc[(IB) + i_][j_] = __builtin_amdgcn_mfma_f32_16x16x32_bf16(  \
                    a_[i_], bfr[j_], acc[(IB) + i_][j_], 0, 0, 0);             \
        __builtin_amdgcn_s_setprio(0);                                         \
        RAW_BAR();                                                             \
    } while (0)

    // prologue: tile0 all 4 regions + tile1 A0,B0 (12 loads); oldest 4 (=tile0
    // A0,B0) must land before P0(0): allow newest 8.
    stageA(0, 0); stageB(0, 0); stageA(0, 1); stageB(0, 1);
    stageA(1, 0); stageB(1, 0);
    WAITV(8);
    RAW_BAR();

#pragma unroll 1
    for (int t = 0; t < 64; ++t) {
        const char* seg = smem + ((t & 1) << 16);
        PHASE(seg, 0, 0, true,  { stageA(t + 1, 1); }, {});            // P0
        PHASE(seg, 0, 4, false, { stageB(t + 1, 1); }, { WAITV(8); }); // P1
        PHASE(seg, 1, 0, true,  { stageA(t + 2, 0); }, {});            // P2
        PHASE(seg, 1, 4, false, { stageB(t + 2, 0); }, { WAITV(8); }); // P3
    }
    // tile 64 (dbuf 0): stage only A1(65), B1(65)
    {
        const char* seg = smem;
        PHASE(seg, 0, 0, true,  { stageA(65, 1); }, {});
        PHASE(seg, 0, 4, false, { stageB(65, 1); }, { WAITV(8); });
        PHASE(seg, 1, 0, true,  {}, {});
        PHASE(seg, 1, 4, false, {}, { WAITV(4); });
    }
    // tile 65 (dbuf 1): drain
    {
        const char* seg = smem + 65536;
        PHASE(seg, 0, 0, true,  {}, {});
        PHASE(seg, 0, 4, false, {}, { WAITV(0); });
        PHASE(seg, 1, 0, true,  {}, {});
        PHASE(seg, 1, 4, false, {}, {});
    }
#undef PHASE

    const int nl = hl;
#pragma unroll
    for (int j = 0; j < 4; ++j) {
        const int n = nb * 256 + wn * 64 + j * 16 + nl;
        const float bz = bbf[n];
#pragma unroll
        for (int i = 0; i < 8; ++i) {
            const int m = mb * 256 + wm * 128 + i * 16 + quad * 4;
            float* dst = out + (size_t)m * DOUT + n;
#pragma unroll
            for (int r = 0; r < 4; ++r)
                dst[(size_t)r * DOUT] = acc[i][j][r] + bz;
        }
    }
}

extern "C" void kernel_launch(void* const* d_in, const int* in_sizes, int n_in,
                              void* d_out, int out_size, void* d_ws, size_t ws_size,
                              hipStream_t stream) {
    const float* x      = (const float*)d_in[0];
    const float* gate_w = (const float*)d_in[1];
    const float* base_w = (const float*)d_in[2];
    const float* base_b = (const float*)d_in[3];
    const float* lora_A = (const float*)d_in[4];
    const float* lora_B = (const float*)d_in[5];
    float* out = (float*)d_out;

    char* ws = (char*)d_ws;
    u16*   xb    = (u16*)(ws + OFF_XB);
    u16*   wb    = (u16*)(ws + OFF_WB);
    u16*   ab    = (u16*)(ws + OFF_AB);
    u16*   bs2   = (u16*)(ws + OFF_BS2);
    u16*   U     = (u16*)(ws + OFF_U);
    float* bbf   = (float*)(ws + OFF_BBF);
    float* Lg    = (float*)(ws + OFF_LG);
    float* Gpart = (float*)(ws + OFF_GPART);

    static bool attr_done = false;
    if (!attr_done) {
        (void)hipFuncSetAttribute(reinterpret_cast<const void*>(gemm2),
                                  hipFuncAttributeMaxDynamicSharedMemorySize, 131072);
        attr_done = true;
    }

    prep_x<<<T_TOK / 16, 256, 0, stream>>>(x, gate_w, xb, Lg);
    convert_w_pack<<<8192 + 4112, 256, 0, stream>>>(base_w, lora_A, lora_B, base_b,
                                                    (uint4*)wb, ab, bs2, bbf);
    gemm1<<<dim3(32, SPLIT), 256, 0, stream>>>(xb, ab, Gpart);
    route_u<<<T_TOK / 16, 256, 0, stream>>>(Gpart, Lg, U);
    gemm2<<<256, 512, 131072, stream>>>(xb, wb, bbf, U, bs2, out);
}

// Round 6
// 317.290 us; speedup vs baseline: 1.6864x; 1.0532x over previous
//
#include <hip/hip_runtime.h>
#include <hip/hip_bf16.h>

typedef unsigned short u16;
typedef __bf16  bf16x8 __attribute__((ext_vector_type(8)));
typedef float   f32x4  __attribute__((ext_vector_type(4)));

#define T_TOK 4096   // B*S tokens
#define DIN   4096
#define DOUT  4096
#define NEXP  8
#define ER    128    // E*R
#define SPLIT 8
#define KCH   (DIN / SPLIT)   // 512

// ws layout (bytes)
#define OFF_XB    0u           // bf16 x            33,554,432
#define OFF_WB    33554432u    // bf16 base_w       33,554,432
#define OFF_AB    67108864u    // bf16 lora_A flat   1,048,576
#define OFF_BS2   68157440u    // bf16 2*lora_B^T    1,048,576
#define OFF_U     69206016u    // bf16 U             1,048,576
#define OFF_BBF   70254592u    // fp32 bias             16,384
#define OFF_LG    70270976u    // fp32 logits          131,072
#define OFF_GPART 70402048u    // fp32 partials     16,777,216  -> end 87,179,264

__device__ __forceinline__ void async16(void* lds, const void* g) {
    __builtin_amdgcn_global_load_lds(
        (const __attribute__((address_space(1))) void*)g,
        (__attribute__((address_space(3))) void*)lds,
        16, 0, 0);
}

static __device__ __forceinline__ u16 f2b(float f) {
    __hip_bfloat16 h = __float2bfloat16(f);
    return *(u16*)&h;
}

// XOR-swizzled LDS read (128B rows, used by gemm1): slot (row, g') holds global
// column-group g'^ (row&7).
__device__ __forceinline__ bf16x8 lds8(const u16* base, int row, int grp) {
    return *(const bf16x8*)((const char*)base + row * 128 + (((grp ^ row) & 7) * 16));
}

// scheduling / sync primitives for the counted-vmcnt pipeline
#define FENCE() asm volatile("" ::: "memory")
#define RAW_BAR() do { FENCE(); __builtin_amdgcn_s_barrier(); FENCE(); } while (0)
#define LGKM0() do { asm volatile("s_waitcnt lgkmcnt(0)" ::: "memory"); \
                     __builtin_amdgcn_sched_barrier(0); } while (0)
#define WAITV(N) do { asm volatile("s_waitcnt vmcnt(" #N ")" ::: "memory"); \
                      __builtin_amdgcn_sched_barrier(0); } while (0)

// ---------------- prep_all: one launch for all preprocessing.
// blocks [0,512):      x fp32 -> xb bf16 + gate logits (2 tokens/wave)
// blocks [512,8704):   base_w fp32 -> wb bf16
// blocks [8704,12816): lora_A / lora_B^T / bias packs
__global__ __launch_bounds__(256) void prep_all(const float* __restrict__ x,
                                                const float* __restrict__ gw,
                                                const float* __restrict__ wsrc,
                                                const float* __restrict__ lora_A,
                                                const float* __restrict__ lora_B,
                                                const float* __restrict__ base_b,
                                                u16* __restrict__ xb,
                                                float* __restrict__ Lg,
                                                uint4* __restrict__ wb,
                                                u16* __restrict__ ab,
                                                u16* __restrict__ bs2,
                                                float* __restrict__ bbf) {
    const int bid = blockIdx.x;
    if (bid < 512) {
        const int w = threadIdx.x >> 6, lid = threadIdx.x & 63;
        const int t0 = (bid * 4 + w) * 2;
        float acc[2][8];
#pragma unroll
        for (int j = 0; j < 2; ++j)
#pragma unroll
            for (int e = 0; e < 8; ++e) acc[j][e] = 0.f;
        for (int i = lid; i < DIN / 4; i += 64) {
            float4 gv[8];
#pragma unroll
            for (int e = 0; e < 8; ++e)
                gv[e] = ((const float4*)(gw + (size_t)e * DIN))[i];
#pragma unroll
            for (int j = 0; j < 2; ++j) {
                float4 xv = ((const float4*)(x + (size_t)(t0 + j) * DIN))[i];
                ushort4 o = { f2b(xv.x), f2b(xv.y), f2b(xv.z), f2b(xv.w) };
                ((ushort4*)(xb + (size_t)(t0 + j) * DIN))[i] = o;
#pragma unroll
                for (int e = 0; e < 8; ++e)
                    acc[j][e] += xv.x * gv[e].x + xv.y * gv[e].y + xv.z * gv[e].z + xv.w * gv[e].w;
            }
        }
#pragma unroll
        for (int j = 0; j < 2; ++j)
#pragma unroll
            for (int e = 0; e < 8; ++e) {
                float v = acc[j][e];
                for (int off = 32; off; off >>= 1) v += __shfl_down(v, off, 64);
                if (lid == 0) Lg[(t0 + j) * 8 + e] = v;
            }
    } else if (bid < 8704) {
        int li = (bid - 512) * 256 + threadIdx.x;    // 2,097,152 threads
        const float4* s = (const float4*)wsrc;
        float4 a = s[2 * li], b = s[2 * li + 1];
        uint4 o;
        o.x = (unsigned)f2b(a.x) | ((unsigned)f2b(a.y) << 16);
        o.y = (unsigned)f2b(a.z) | ((unsigned)f2b(a.w) << 16);
        o.z = (unsigned)f2b(b.x) | ((unsigned)f2b(b.y) << 16);
        o.w = (unsigned)f2b(b.z) | ((unsigned)f2b(b.w) << 16);
        wb[li] = o;
    } else {
        int idx = (bid - 8704) * 256 + threadIdx.x;   // total 1,052,672
        if (idx < 524288) {                          // lora_A flat copy [e*16+r][d]
            ab[idx] = f2b(lora_A[idx]);
        } else if (idx < 1048576) {                  // bs2[o, e*16+r] = 2*lora_B[e,o,r]
            int j = idx - 524288;
            int o = j >> 7, c = j & 127, e = c >> 4, r = c & 15;
            bs2[j] = f2b(lora_B[(e * DOUT + o) * 16 + r] * 2.0f);
        } else if (idx < 1052672) {
            int j = idx - 1048576;
            bbf[j] = base_b[j];
        }
    }
}

// ---------------- GEMM1: Gpart[s] = X @ lora_A^T, split-K fp32 partials
// grid (32 mb, 8 split), block 256. Tile 128(M) x 128(N) x 64(K).
__global__ __launch_bounds__(256) void gemm1(const u16* __restrict__ X,
                                             const u16* __restrict__ ab,
                                             float* __restrict__ Gpart) {
    __shared__ __align__(16) u16 As[128 * 64];
    __shared__ __align__(16) u16 Bs[128 * 64];
    const int mb = blockIdx.x, s = blockIdx.y;
    const int w = threadIdx.x >> 6, lid = threadIdx.x & 63;
    const int lrow = lid >> 3;                    // row within 8-row chunk
    const int lcolb = ((lid & 7) ^ lrow) * 16;    // swizzled source column group

    f32x4 acc[2][8];
#pragma unroll
    for (int i = 0; i < 2; ++i)
#pragma unroll
        for (int j = 0; j < 8; ++j) acc[i][j] = (f32x4){0.f, 0.f, 0.f, 0.f};

    int k0 = s * KCH;
    for (int kt = 0; kt < KCH / 64; ++kt, k0 += 64) {
#pragma unroll
        for (int q = 0; q < 4; ++q) {
            int c = w * 4 + q;
            int arow = mb * 128 + c * 8 + lrow;
            async16((char*)As + c * 1024,
                    (const char*)X + ((size_t)arow * DIN + k0) * 2 + lcolb);
            async16((char*)Bs + c * 1024,
                    (const char*)ab + ((size_t)(c * 8 + lrow) * DIN + k0) * 2 + lcolb);
        }
        __syncthreads();
        const int quad = lid >> 4, half = lid & 15;
#pragma unroll
        for (int ks8 = 0; ks8 < 8; ks8 += 4) {
            bf16x8 a[2], b[8];
#pragma unroll
            for (int i = 0; i < 2; ++i)
                a[i] = lds8(As, w * 32 + i * 16 + half, ks8 + quad);
#pragma unroll
            for (int j = 0; j < 8; ++j)
                b[j] = lds8(Bs, j * 16 + half, ks8 + quad);
#pragma unroll
            for (int i = 0; i < 2; ++i)
#pragma unroll
                for (int j = 0; j < 8; ++j)
                    acc[i][j] = __builtin_amdgcn_mfma_f32_16x16x32_bf16(a[i], b[j], acc[i][j], 0, 0, 0);
        }
        __syncthreads();
    }
    const int quad = lid >> 4, nl = lid & 15;
#pragma unroll
    for (int i = 0; i < 2; ++i)
#pragma unroll
        for (int j = 0; j < 8; ++j) {
            int n = j * 16 + nl;
            int t = mb * 128 + w * 32 + i * 16 + quad * 4;
            float* dst = Gpart + ((size_t)s * T_TOK + t) * ER + n;
#pragma unroll
            for (int r = 0; r < 4; ++r) dst[(size_t)r * ER] = acc[i][j][r];
        }
}

// ---------------- routing: top-2 softmax (fp32 logits), build U (vectorized) ----------------
__global__ __launch_bounds__(256) void route_u(const float* __restrict__ Gpart,
                                               const float* __restrict__ Lg,
                                               u16* __restrict__ U) {
    __shared__ float wmap[16][9];
    const int t0 = blockIdx.x * 16;
    const int tid = threadIdx.x;
    if (tid < 16) {
        float l[8];
#pragma unroll
        for (int e = 0; e < 8; ++e) l[e] = Lg[(t0 + tid) * 8 + e];
        int e1 = 0; float b1 = l[0];
#pragma unroll
        for (int e = 1; e < 8; ++e) if (l[e] > b1) { b1 = l[e]; e1 = e; }
        int e2 = -1; float b2 = -3.4e38f;
#pragma unroll
        for (int e = 0; e < 8; ++e) if (e != e1 && l[e] > b2) { b2 = l[e]; e2 = e; }
        float ex = __expf(b2 - b1);
        float inv = 1.f / (1.f + ex);
#pragma unroll
        for (int e = 0; e < 8; ++e) wmap[tid][e] = 0.f;
        wmap[tid][e1] = inv;
        wmap[tid][e2] = ex * inv;
    }
    __syncthreads();
#pragma unroll
    for (int it = 0; it < 2; ++it) {
        int idx = it * 256 + tid;          // 16 tokens * 32 float4-cols
        int tl = idx >> 5, c4 = idx & 31;
        float4 s = {0.f, 0.f, 0.f, 0.f};
        for (int sp = 0; sp < SPLIT; ++sp) {
            float4 g = ((const float4*)(Gpart + ((size_t)sp * T_TOK + t0 + tl) * ER))[c4];
            s.x += g.x; s.y += g.y; s.z += g.z; s.w += g.w;
        }
        float wv = wmap[tl][c4 >> 2];
        ushort4 o = { f2b(s.x * wv), f2b(s.y * wv), f2b(s.z * wv), f2b(s.w * wv) };
        ((ushort4*)(U + (size_t)(t0 + tl) * ER))[c4] = o;
    }
}

// ---------------- GEMM2: out = [X|U] @ [W|Bs2]^T + bias, fp32 out ----------------
// 256x256 tile, 8 waves (2M x 4N), BK=64. Single-barrier 4-phase/K-tile schedule.
// LDS (128 KiB dynamic): 2 dbufs x { A_ks0 | A_ks1 | B_ks0 | B_ks1 }, 16 KB each.
// Phase = { ds_read frags ; stage 1 region ; [WAITV] ; barrier ; lgkmcnt(0) ;
//           setprio(1) 16 MFMA setprio(0) ; sched_barrier }.   (NO trailing barrier)
// Stage plan rotated so every staged region's old content was last READ two
// phases earlier: P0->B1(t+1) [last read P2(t-1)], P1->A1(t+1) [P3(t-1)],
// P2->B0(t+2) [P0(t)], P3->A0(t+2) [P1(t)].
// Safety: a wave executing stage(P) has passed BAR(P-1); BAR(P-1) released only
// after every wave reached it, i.e. executed LGKM0(P-2) (it precedes MFMA(P-2)
// which precedes reads(P-1)) -> all reads of the staged region are drained.
// Landing guarantee: reads(P) target a region whose loads (all waves) were
// retired by a WAITV that precedes a BAR which precedes reads(P).
// vmcnt ledger (loads/thread): prologue 12 issued oldest-first
// {A0(0),B0(0) | A1(0),B1(0) | B0(1),A0(1)}; WAITV(8) lands A0/B0(0).
// Steady state: WV(8)@P1 retires A1(t),B1(t) (needed P2(t)); WV(8)@P3 retires
// B0(t+1),A0(t+1) (needed P0(t+1)). Wind-down: P3(64) WV(4), P1(65) WV(0).
__global__ __launch_bounds__(512) void gemm2(const u16* __restrict__ X,
                                             const u16* __restrict__ W,
                                             const float* __restrict__ bbf,
                                             const u16* __restrict__ U,
                                             const u16* __restrict__ Bs2,
                                             float* __restrict__ out) {
    extern __shared__ __align__(16) char smem[];
    const int tid = threadIdx.x;
    const int l = tid & 63, w = tid >> 6;        // 8 waves
    const int wm = w & 1, wn = w >> 1;           // 2M x 4N wave grid

    // XCD-bijective swizzle: 256 wg = 8 xcd * 32.
    const int bid = blockIdx.x;
    const int sw = (bid & 7) * 32 + (bid >> 3);
    const int mb = sw >> 4, nb = sw & 15;

    // staging geometry (per-lane global source; LDS dest = wave-uniform + lane*16)
    const int srow = w * 16 + (l >> 2);                     // 0..127 per round
    const int gcol = (((l & 3) ^ ((l >> 3) & 3)) << 3);     // pre-swizzled col (elems)
    const int ldso = w * 1024;                              // wave-uniform LDS offset

    // frag-read geometry
    const int hl = l & 15, quad = l >> 4;
    const int sgr = ((quad ^ ((hl >> 1) & 3)) << 4);        // swizzled 16B slot
    const int rbA = (wm * 128 + hl) * 64 + sgr;
    const int rbB = (wn * 64 + hl) * 64 + sgr;

    const u16* xrow = X   + (size_t)(mb * 256 + srow) * DIN;
    const u16* wrw  = W   + (size_t)(nb * 256 + srow) * DIN;
    const u16* urow = U   + (size_t)(mb * 256 + srow) * ER;
    const u16* brow = Bs2 + (size_t)(nb * 256 + srow) * ER;

    f32x4 acc[8][4];
#pragma unroll
    for (int i = 0; i < 8; ++i)
#pragma unroll
        for (int j = 0; j < 4; ++j) acc[i][j] = (f32x4){0.f, 0.f, 0.f, 0.f};

    // stage one 16 KB region (2 loads/thread). t2 selects dbuf via parity.
    auto stageA = [&](int t2, int ks) {
        char* dst = smem + ((t2 & 1) << 16) + (ks << 14) + ldso;
        if (t2 < 64) {
            const int col = t2 * 64 + ks * 32 + gcol;
            async16(dst,        xrow + col);
            async16(dst + 8192, xrow + (size_t)128 * DIN + col);
        } else {
            const int col = (t2 - 64) * 64 + ks * 32 + gcol;
            async16(dst,        urow + col);
            async16(dst + 8192, urow + 128 * ER + col);
        }
    };
    auto stageB = [&](int t2, int ks) {
        char* dst = smem + ((t2 & 1) << 16) + 32768 + (ks << 14) + ldso;
        if (t2 < 64) {
            const int col = t2 * 64 + ks * 32 + gcol;
            async16(dst,        wrw + col);
            async16(dst + 8192, wrw + (size_t)128 * DIN + col);
        } else {
            const int col = (t2 - 64) * 64 + ks * 32 + gcol;
            async16(dst,        brow + col);
            async16(dst + 8192, brow + 128 * ER + col);
        }
    };

    bf16x8 bfr[4];   // b-frags held across each phase pair (read once per k-slice)

    // PHASE: reads, stage, [waitv], ONE barrier, lgkm0, MFMA, sched-fence.
#define PHASE(SEG, KS, IB, READB, STAGE, WV) do {                              \
        const char* rs_ = (SEG) + ((KS) << 14);                                \
        bf16x8 a_[4];                                                          \
        _Pragma("unroll")                                                      \
        for (int i_ = 0; i_ < 4; ++i_)                                         \
            a_[i_] = *(const bf16x8*)(rs_ + rbA + ((IB) + i_) * 1024);         \
        if (READB) {                                                           \
            _Pragma("unroll")                                                  \
            for (int j_ = 0; j_ < 4; ++j_)                                     \
                bfr[j_] = *(const bf16x8*)(rs_ + 32768 + rbB + j_ * 1024);     \
        }                                                                      \
        STAGE;                                                                 \
        WV;                                                                    \
        RAW_BAR();                                                             \
        LGKM0();                                                               \
        __builtin_amdgcn_s_setprio(1);                                         \
        _Pragma("unroll")                                                      \
        for (int i_ = 0; i_ < 4; ++i_)                                         \
            _Pragma("unroll")                                                  \
            for (int j_ = 0; j_ < 4; ++j_)                                     \
                acc[(IB) + i_][j_] = __builtin_amdgcn_mfma_f32_16x16x32_bf16(  \
                    a_[i_], bfr[j_], acc[(IB) + i_][j_], 0, 0, 0);             \
        __builtin_amdgcn_s_setprio(0);                                         \
        __builtin_amdgcn_sched_barrier(0);                                     \
    } while (0)

    // prologue — issue order matters for WAITV retirement (oldest first):
    stageA(0, 0); stageB(0, 0);      // A0(0),B0(0)  (retired by WAITV(8) below)
    stageA(0, 1); stageB(0, 1);      // A1(0),B1(0)  (retired @ P1(0) WV8)
    stageB(1, 0); stageA(1, 0);      // B0(1),A0(1)  (retired @ P3(0) WV8)
    WAITV(8);
    RAW_BAR();

#pragma unroll 1
    for (int t = 0; t < 64; ++t) {
        const char* seg = smem + ((t & 1) << 16);
        PHASE(seg, 0, 0, true,  { stageB(t + 1, 1); }, {});            // P0
        PHASE(seg, 0, 4, false, { stageA(t + 1, 1); }, { WAITV(8); }); // P1
        PHASE(seg, 1, 0, true,  { stageB(t + 2, 0); }, {});            // P2
        PHASE(seg, 1, 4, false, { stageA(t + 2, 0); }, { WAITV(8); }); // P3
    }
    // tile 64 (dbuf 0): stage only B1(65), A1(65)
    {
        const char* seg = smem;
        PHASE(seg, 0, 0, true,  { stageB(65, 1); }, {});
        PHASE(seg, 0, 4, false, { stageA(65, 1); }, { WAITV(8); });
        PHASE(seg, 1, 0, true,  {}, {});
        PHASE(seg, 1, 4, false, {}, { WAITV(4); });
    }
    // tile 65 (dbuf 1): drain
    {
        const char* seg = smem + 65536;
        PHASE(seg, 0, 0, true,  {}, {});
        PHASE(seg, 0, 4, false, {}, { WAITV(0); });
        PHASE(seg, 1, 0, true,  {}, {});
        PHASE(seg, 1, 4, false, {}, {});
    }
#undef PHASE

    const int nl = hl;
#pragma unroll
    for (int j = 0; j < 4; ++j) {
        const int n = nb * 256 + wn * 64 + j * 16 + nl;
        const float bz = bbf[n];
#pragma unroll
        for (int i = 0; i < 8; ++i) {
            const int m = mb * 256 + wm * 128 + i * 16 + quad * 4;
            float* dst = out + (size_t)m * DOUT + n;
#pragma unroll
            for (int r = 0; r < 4; ++r)
                dst[(size_t)r * DOUT] = acc[i][j][r] + bz;
        }
    }
}

extern "C" void kernel_launch(void* const* d_in, const int* in_sizes, int n_in,
                              void* d_out, int out_size, void* d_ws, size_t ws_size,
                              hipStream_t stream) {
    const float* x      = (const float*)d_in[0];
    const float* gate_w = (const float*)d_in[1];
    const float* base_w = (const float*)d_in[2];
    const float* base_b = (const float*)d_in[3];
    const float* lora_A = (const float*)d_in[4];
    const float* lora_B = (const float*)d_in[5];
    float* out = (float*)d_out;

    char* ws = (char*)d_ws;
    u16*   xb    = (u16*)(ws + OFF_XB);
    u16*   wb    = (u16*)(ws + OFF_WB);
    u16*   ab    = (u16*)(ws + OFF_AB);
    u16*   bs2   = (u16*)(ws + OFF_BS2);
    u16*   U     = (u16*)(ws + OFF_U);
    float* bbf   = (float*)(ws + OFF_BBF);
    float* Lg    = (float*)(ws + OFF_LG);
    float* Gpart = (float*)(ws + OFF_GPART);

    static bool attr_done = false;
    if (!attr_done) {
        (void)hipFuncSetAttribute(reinterpret_cast<const void*>(gemm2),
                                  hipFuncAttributeMaxDynamicSharedMemorySize, 131072);
        attr_done = true;
    }

    prep_all<<<12816, 256, 0, stream>>>(x, gate_w, base_w, lora_A, lora_B, base_b,
                                        xb, Lg, (uint4*)wb, ab, bs2, bbf);
    gemm1<<<dim3(32, SPLIT), 256, 0, stream>>>(xb, ab, Gpart);
    route_u<<<T_TOK / 16, 256, 0, stream>>>(Gpart, Lg, U);
    gemm2<<<256, 512, 131072, stream>>>(xb, wb, bbf, U, bs2, out);
}